// Round 9
// baseline (61.565 us; speedup 1.0000x reference)
//
#include <hip/hip_runtime.h>
#include <math.h>

#define KROOTS 16
#define NC 17        // K+1 coefficients
#define BLK 64       // one wave per block
#define NSTORE_REP 40  // INSTRUMENTATION: slope-calibrated (1.14us/pass, R8)
                       // to push dispatch ~50us > 42us fills -> rocprof top-5

// Real-parts-only output (17 floats/row), per-wave LDS store staging.
// INSTRUMENTATION ROUND 2: measure F = dur_us - dispatch(End-Start)
// -> true single-shot kernel time T7 = 13.15 - F.
template <int MODE>
__global__ __launch_bounds__(BLK) void encoder_vieta_kernel(
    const float* __restrict__ x,
    const float* __restrict__ shuffle,
    float* __restrict__ out,
    int B)
{
    __shared__ float sc[KROOTS], ss[KROOTS];
    __shared__ float so[BLK * NC];   // 4,352 B per-wave store staging

    const int tid = threadIdx.x;
    if (tid < KROOTS) {
        float phi = shuffle[tid];
        sc[tid] = cosf(phi);
        ss[tid] = sinf(phi);
    }
    __syncthreads();

    const int b = blockIdx.x * BLK + tid;
    if (b >= B) return;

    // R = sqrt(1 + sin(pi/16)) (learnable_radius=False)
    const float R    = 1.09320186720915563f;
    const float invR = 0.91474476120342423f;

    const float4* xp = reinterpret_cast<const float4*>(x + (size_t)b * KROOTS);
    float xr[KROOTS];
    #pragma unroll
    for (int i = 0; i < 4; ++i) {
        float4 v = xp[i];
        xr[4 * i + 0] = v.x;
        xr[4 * i + 1] = v.y;
        xr[4 * i + 2] = v.z;
        xr[4 * i + 3] = v.w;
    }

    float cr[NC], ci[NC];
    cr[0] = 1.0f; ci[0] = 0.0f;
    #pragma unroll
    for (int d = 1; d < NC; ++d) { cr[d] = 0.0f; ci[d] = 0.0f; }

    #pragma unroll
    for (int j = 0; j < KROOTS; ++j) {
        const float rad = (xr[j] > 0.0f) ? R : invR;
        const float rr = rad * sc[j];
        const float ri = rad * ss[j];
        #pragma unroll
        for (int d = j + 1; d >= 1; --d) {
            const float ar = cr[d - 1], ai = ci[d - 1];
            cr[d] = fmaf(-rr, ar, fmaf( ri, ai, cr[d]));
            ci[d] = fmaf(-rr, ai, fmaf(-ri, ar, ci[d]));
        }
    }

    float sum = 0.0f;
    #pragma unroll
    for (int d = 0; d < NC; ++d)
        sum = fmaf(cr[d], cr[d], fmaf(ci[d], ci[d], sum));
    const float scale = sqrtf(17.0f) * __frsqrt_rn(sum);

    if (MODE == 0) {
        float2* op = reinterpret_cast<float2*>(out + (size_t)b * 2 * NC);
        #pragma unroll
        for (int d = 0; d < NC; ++d)
            op[d] = make_float2(cr[d] * scale, ci[d] * scale);
    } else {
        // stage real parts: stride 17 floats (odd -> 2 lanes/bank, free)
        #pragma unroll
        for (int d = 0; d < NC; ++d)
            so[tid * NC + d] = cr[d] * scale;
        __syncthreads();

        const size_t blk_f4 = (size_t)blockIdx.x * (BLK * NC / 4);
        float4* og = reinterpret_cast<float4*>(out) + blk_f4;
        const float4* sg = reinterpret_cast<const float4*>(so);
        // INSTRUMENTATION: idempotent store passes; memory clobber keeps
        // each pass's stores live (prevents dead-store elimination).
        #pragma unroll 1
        for (int r = 0; r < NSTORE_REP; ++r) {
            #pragma unroll
            for (int i = tid; i < BLK * NC / 4; i += BLK)
                og[i] = sg[i];
            asm volatile("" ::: "memory");
        }
    }
}

extern "C" void kernel_launch(void* const* d_in, const int* in_sizes, int n_in,
                              void* d_out, int out_size, void* d_ws, size_t ws_size,
                              hipStream_t stream) {
    const float* x       = (const float*)d_in[0];
    const float* shuffle = (const float*)d_in[1];
    float* out = (float*)d_out;
    const int B = in_sizes[0] / KROOTS;
    const int grid = (B + BLK - 1) / BLK;
    if (out_size >= 2 * NC * B) {
        encoder_vieta_kernel<0><<<grid, BLK, 0, stream>>>(x, shuffle, out, B);
    } else {
        encoder_vieta_kernel<1><<<grid, BLK, 0, stream>>>(x, shuffle, out, B);
    }
}

// Round 11
// 13.458 us; speedup vs baseline: 4.5746x; 4.5746x over previous
//
#include <hip/hip_runtime.h>
#include <math.h>

#define KROOTS 16
#define NC 17        // K+1 coefficients
#define BLK 64       // one wave per block
#define NCOMP_REP 20 // INSTRUMENTATION: repeat Vieta compute to measure VALU slope

// Opaque identity: compiler cannot CSE across reps, value unchanged.
__device__ __forceinline__ float opaque_f(float v) {
    asm volatile("" : "+v"(v));
    return v;
}

// Real-parts-only output (17 floats/row), per-wave LDS store staging.
// INSTRUMENTATION ROUND 3: compute repeated NCOMP_REP times (identical result)
// -> marginal slope = pure compute cost per pass. Single store pass.
template <int MODE>
__global__ __launch_bounds__(BLK) void encoder_vieta_kernel(
    const float* __restrict__ x,
    const float* __restrict__ shuffle,
    float* __restrict__ out,
    int B)
{
    __shared__ float sc[KROOTS], ss[KROOTS];
    __shared__ float so[BLK * NC];   // 4,352 B per-wave store staging

    const int tid = threadIdx.x;
    if (tid < KROOTS) {
        float phi = shuffle[tid];
        sc[tid] = cosf(phi);
        ss[tid] = sinf(phi);
    }
    __syncthreads();

    const int b = blockIdx.x * BLK + tid;
    if (b >= B) return;

    // R = sqrt(1 + sin(pi/16)) (learnable_radius=False)
    const float R    = 1.09320186720915563f;
    const float invR = 0.91474476120342423f;

    const float4* xp = reinterpret_cast<const float4*>(x + (size_t)b * KROOTS);
    float xr[KROOTS];
    #pragma unroll
    for (int i = 0; i < 4; ++i) {
        float4 v = xp[i];
        xr[4 * i + 0] = v.x;
        xr[4 * i + 1] = v.y;
        xr[4 * i + 2] = v.z;
        xr[4 * i + 3] = v.w;
    }

    float cr[NC], ci[NC];
    float scale = 0.0f;

    // INSTRUMENTATION: rep loop NOT unrolled (I-cache); each rep recomputes
    // the full recurrence because xr[0] passes through an opaque identity.
    #pragma unroll 1
    for (int rep = 0; rep < NCOMP_REP; ++rep) {
        xr[0] = opaque_f(xr[0]);

        cr[0] = 1.0f; ci[0] = 0.0f;
        #pragma unroll
        for (int d = 1; d < NC; ++d) { cr[d] = 0.0f; ci[d] = 0.0f; }

        #pragma unroll
        for (int j = 0; j < KROOTS; ++j) {
            const float rad = (xr[j] > 0.0f) ? R : invR;
            const float rr = rad * sc[j];
            const float ri = rad * ss[j];
            #pragma unroll
            for (int d = j + 1; d >= 1; --d) {
                const float ar = cr[d - 1], ai = ci[d - 1];
                cr[d] = fmaf(-rr, ar, fmaf( ri, ai, cr[d]));
                ci[d] = fmaf(-rr, ai, fmaf(-ri, ar, ci[d]));
            }
        }

        float sum = 0.0f;
        #pragma unroll
        for (int d = 0; d < NC; ++d)
            sum = fmaf(cr[d], cr[d], fmaf(ci[d], ci[d], sum));
        scale = sqrtf(17.0f) * __frsqrt_rn(sum);
    }

    if (MODE == 0) {
        float2* op = reinterpret_cast<float2*>(out + (size_t)b * 2 * NC);
        #pragma unroll
        for (int d = 0; d < NC; ++d)
            op[d] = make_float2(cr[d] * scale, ci[d] * scale);
    } else {
        // stage real parts: stride 17 floats (odd -> 2 lanes/bank, free)
        #pragma unroll
        for (int d = 0; d < NC; ++d)
            so[tid * NC + d] = cr[d] * scale;
        __syncthreads();

        const size_t blk_f4 = (size_t)blockIdx.x * (BLK * NC / 4);
        float4* og = reinterpret_cast<float4*>(out) + blk_f4;
        const float4* sg = reinterpret_cast<const float4*>(so);
        #pragma unroll
        for (int i = tid; i < BLK * NC / 4; i += BLK)   // 272 f4 -> 4.25/thread
            og[i] = sg[i];
    }
}

extern "C" void kernel_launch(void* const* d_in, const int* in_sizes, int n_in,
                              void* d_out, int out_size, void* d_ws, size_t ws_size,
                              hipStream_t stream) {
    const float* x       = (const float*)d_in[0];
    const float* shuffle = (const float*)d_in[1];
    float* out = (float*)d_out;
    const int B = in_sizes[0] / KROOTS;
    const int grid = (B + BLK - 1) / BLK;
    if (out_size >= 2 * NC * B) {
        encoder_vieta_kernel<0><<<grid, BLK, 0, stream>>>(x, shuffle, out, B);
    } else {
        encoder_vieta_kernel<1><<<grid, BLK, 0, stream>>>(x, shuffle, out, B);
    }
}